// Round 7
// baseline (722.259 us; speedup 1.0000x reference)
//
#include <hip/hip_runtime.h>
#include <math.h>

#define NN 50000
#define EE 800000
#define DD 32

// deg packing: one double atomic per edge carries both count and sum(w):
//   pack += 65536.0 + w   ->  count = floor(pack/65536), sumw = pack - 65536*count
__device__ __forceinline__ int pack_count(double p){ return (int)(p * (1.0/65536.0)); }
__device__ __forceinline__ float pack_sumw(double p){ return (float)(p - 65536.0 * (double)pack_count(p)); }

// ---------------- setup kernels ----------------

__global__ __launch_bounds__(256) void k_zero(float* p, int count){
  int i = blockIdx.x*256 + threadIdx.x;
  if (i < count) p[i] = 0.f;
}

__global__ __launch_bounds__(256) void k_hist(const int* __restrict__ node_out,
                                              const float* __restrict__ ew,
                                              double* __restrict__ deg_pack){
  int e = blockIdx.x*256 + threadIdx.x;
  if (e < EE){
    int o = node_out[e];
    atomicAdd(&deg_pack[o], 65536.0 + (double)ew[e]);
  }
}

__global__ __launch_bounds__(256) void k_logsum(const double* __restrict__ deg_pack,
                                                float* __restrict__ logsum){
  __shared__ float sd[256];
  int t = threadIdx.x; int n = blockIdx.x*256 + t;
  float v = 0.f;
  if (n < NN) v = logf(pack_sumw(deg_pack[n]) + 1.f);
  sd[t] = v; __syncthreads();
  for (int off = 128; off > 0; off >>= 1){
    if (t < off) sd[t] += sd[t+off];
    __syncthreads();
  }
  if (t == 0) atomicAdd(logsum, sd[0]);
}

__global__ __launch_bounds__(256) void k_scan1(const double* __restrict__ deg_pack,
                                               int* __restrict__ partials){
  __shared__ int sd[256];
  int t = threadIdx.x; int n = blockIdx.x*256 + t;
  sd[t] = (n < NN) ? pack_count(deg_pack[n]) : 0; __syncthreads();
  for (int off = 128; off > 0; off >>= 1){
    if (t < off) sd[t] += sd[t+off];
    __syncthreads();
  }
  if (t == 0) partials[blockIdx.x] = sd[0];
}

__global__ __launch_bounds__(256) void k_scan2(int* __restrict__ partials, int nb,
                                               int* __restrict__ row_start,
                                               int2* __restrict__ csr){
  __shared__ int sd[256];
  int t = threadIdx.x;
  int v = (t < nb) ? partials[t] : 0;
  sd[t] = v; __syncthreads();
  for (int off = 1; off < 256; off <<= 1){
    int x = (t >= off) ? sd[t-off] : 0;
    __syncthreads();
    sd[t] += x;
    __syncthreads();
  }
  if (t < nb) partials[t] = sd[t] - v;   // exclusive
  if (t == 0) row_start[NN] = EE;
  if (t < 32) csr[EE + t] = make_int2(0, 0);   // zero the pad tail (re-poisoned each call)
}

__global__ __launch_bounds__(256) void k_scan3(const double* __restrict__ deg_pack,
                                               const int* __restrict__ partials,
                                               int* __restrict__ row_start,
                                               int* __restrict__ cursor){
  __shared__ int sd[256];
  int t = threadIdx.x; int n = blockIdx.x*256 + t;
  int v = (n < NN) ? pack_count(deg_pack[n]) : 0;
  sd[t] = v; __syncthreads();
  for (int off = 1; off < 256; off <<= 1){
    int x = (t >= off) ? sd[t-off] : 0;
    __syncthreads();
    sd[t] += x;
    __syncthreads();
  }
  if (n < NN){
    int rs = partials[blockIdx.x] + sd[t] - v;  // exclusive
    row_start[n] = rs; cursor[n] = rs;
  }
}

__global__ __launch_bounds__(256) void k_fillcsr(const int* __restrict__ node_in,
                                                 const int* __restrict__ node_out,
                                                 const float* __restrict__ ew,
                                                 int* __restrict__ cursor,
                                                 int2* __restrict__ csr){
  int e = blockIdx.x*256 + threadIdx.x;
  if (e < EE){
    int o = node_out[e];
    int pos = atomicAdd(&cursor[o], 1);
    int2 v; v.x = node_in[e]; v.y = __float_as_int(ew[e]);
    csr[pos] = v;
  }
}

__global__ __launch_bounds__(256) void k_scales(const double* __restrict__ deg_pack,
                                                const float* __restrict__ logsum,
                                                float* __restrict__ scale_arr,
                                                float* __restrict__ inv_arr){
  int n = blockIdx.x*256 + threadIdx.x;
  if (n < NN){
    float mean = *logsum / (float)NN;
    float s = logf(pack_sumw(deg_pack[n]) + 1.f) / mean;
    scale_arr[n] = s;
    inv_arr[n]   = 1.f / fmaxf(s, 0.01f);
  }
}

// rel_input per layer (6x32) and query-part of final MLP (64)
__global__ __launch_bounds__(256) void k_prep(const float* __restrict__ qw,
                                              const float* __restrict__ rel_W,
                                              const float* __restrict__ rel_b,
                                              const float* __restrict__ W1,
                                              const float* __restrict__ b1,
                                              float* __restrict__ rel6,
                                              float* __restrict__ qc){
  int t = threadIdx.x;
  if (t < 192){
    int l = t >> 5, j = t & 31;
    float s = rel_b[t];
    for (int d = 0; d < 32; ++d) s += qw[d] * rel_W[l*1024 + d*32 + j];
    rel6[t] = s;
  } else if (t < 256){
    int j = t - 192;
    float s = b1[j];
    for (int k = 0; k < 32; ++k) s += qw[k] * W1[(32+k)*64 + j];
    qc[j] = s;
  }
}

__global__ __launch_bounds__(256) void k_init_h(const int* __restrict__ hidx,
                                                float* __restrict__ h,
                                                float* __restrict__ hT){
  int i = blockIdx.x*256 + threadIdx.x;
  int hv = *hidx;
  if (i < NN*DD){
    h[i]  = ((i >> 5) == hv) ? 0.f : 100.f;   // row-major: n = i/32
    int n2 = i % NN;                           // transposed: n = i % N
    hT[i] = (n2 == hv) ? 0.f : 100.f;
  }
}

// t[n] = dot(h[n], rel_layer5) for msg_score
__global__ __launch_bounds__(256) void k_dot(const float* __restrict__ h,
                                             const float* __restrict__ rel6,
                                             float* __restrict__ tdot){
  int n0 = blockIdx.x*256 + threadIdx.x;
  int n = (n0 < NN) ? n0 : NN-1;
  const float* relr = rel6 + 5*32;
  float s = 0.f;
  #pragma unroll
  for (int d = 0; d < 32; ++d) s += h[n*32 + d] * relr[d];
  if (n0 < NN) tdot[n0] = s;
}

// ---------------- fused per-layer kernel ----------------
// Block = 64 nodes, 256 threads, LDS 32768 B, __launch_bounds__(256,3)
// (grid-bound at ~3 blocks/CU; VGPR budget ~168).
// Phase 1: 8 half-wave groups (32 lanes = dim), contiguous CSR range per
//   group. 2-stage software pipeline: csr 2 batches ahead (c/p/q), h & tdot
//   gathers 1 batch ahead -> steady-state loop consumes only values issued a
//   full iteration earlier (no load->use wait). Tail batch guarded
//   separately so the main-loop ACC has no per-edge bounds check. dcnt
//   derived from boundary positions (no per-edge counter).
//   csr is padded with 32 zeroed entries -> all loads unconditional.
// Phase 2: j-split linear (wave-uniform W addresses -> s_load).
template<bool PRED>
__global__ __launch_bounds__(256, 3) void k_layer(const float* __restrict__ h,
                                               const float* __restrict__ hT,
                                               const float* __restrict__ rel6,
                                               const int* __restrict__ row_start,
                                               const int2* __restrict__ csr,
                                               const int* __restrict__ hidx,
                                               const float* __restrict__ tdot,
                                               const float* __restrict__ lin_W,
                                               const float* __restrict__ lin_b,
                                               const float* __restrict__ scale_arr,
                                               const float* __restrict__ inv_arr,
                                               float* __restrict__ h_next,
                                               float* __restrict__ hT_next,
                                               float* __restrict__ pred_out,
                                               int l){
  __shared__ float sh[128*64];
  int tid = threadIdx.x;
  int base = blockIdx.x * 64;
  int hv0 = *hidx;

  // ---- phase 1: aggregation ----
  {
    int g = tid >> 5, lane = tid & 31;
    int ng0 = base + g*8;
    int nend = ((ng0 + 8 <= NN) ? 8 : (NN - ng0));   // nodes in this group
    if (nend > 0){
      float rel = rel6[l*32 + lane];
      auto rsv = [&](int i){ int idx = ng0 + i; return row_start[idx > NN ? NN : idx]; };
      int eBeg = rsv(0), eEnd = rsv(nend);
      // per-node boundary shift register
      int node_beg = eBeg;
      int node_end = rsv(1);
      int nb1 = rsv(2), nb2 = rsv(3), nb3 = rsv(4), nb4 = rsv(5),
          nb5 = rsv(6), nb6 = rsv(7), nb7 = rsv(8);

      int curn = ng0;
      float S1 = 0.f, S2 = 0.f, M = -INFINITY, m = INFINITY;
      float best = -INFINITY; int bi = NN;

#define FINALIZE() do { \
      int dcnt = node_end - node_beg; \
      float bnd = (curn == hv0) ? 0.f : 100.f; \
      float mx, mn; \
      if (dcnt > 0){ \
        float em = (rel >= 0.f) ? rel*M : rel*m; \
        float en = (rel >= 0.f) ? rel*m : rel*M; \
        mx = fmaxf(em, bnd); mn = fminf(en, bnd); \
      } else { mx = bnd; mn = bnd; } \
      float cntf = (float)(dcnt + 1); \
      float mean = (rel*S1 + bnd) / cntf; \
      float sq   = (rel*rel*S2 + bnd*bnd) / cntf; \
      float sdv  = sqrtf(fmaxf(sq - mean*mean, 1e-6f)); \
      int nl = curn - base; \
      int kp0 = lane*4; \
      sh[(kp0+0)*64 + (nl ^ ( kp0   &31))] = mean; \
      sh[(kp0+1)*64 + (nl ^ ((kp0+1)&31))] = mx; \
      sh[(kp0+2)*64 + (nl ^ ((kp0+2)&31))] = mn; \
      sh[(kp0+3)*64 + (nl ^ ((kp0+3)&31))] = sdv; \
      if (PRED){ \
        float ss = (curn == hv0) ? 0.f : 3200.f; \
        if (ss > best){ best = ss; bi = curn; } \
        else if (ss == best && curn < bi) bi = curn; \
        if (lane == 0) pred_out[curn] = (float)bi; \
      } \
      S1 = 0.f; S2 = 0.f; M = -INFINITY; m = INFINITY; \
      best = -INFINITY; bi = NN; \
      ++curn; \
      node_beg = node_end; \
      node_end = nb1; nb1 = nb2; nb2 = nb3; nb3 = nb4; \
      nb4 = nb5; nb5 = nb6; nb6 = nb7; \
    } while(0)

#define ACCU(J, CJ, HJ, TJ) do { \
        int ee = e + J; \
        while (ee >= node_end) FINALIZE(); \
        float w = __int_as_float(CJ.y); \
        float wm = w * HJ; \
        S1 += wm; S2 += wm * HJ; \
        M = fmaxf(M, wm); m = fminf(m, wm); \
        if (PRED){ \
          float sv = w * TJ; \
          if (sv > best){ best = sv; bi = CJ.x; } \
          else if (sv == best && CJ.x < bi) bi = CJ.x; \
        } } while(0)

#define ACCG(J, CJ, HJ, TJ) do { \
        int ee = e + J; \
        if (ee < eEnd){ \
          while (ee >= node_end) FINALIZE(); \
          float w = __int_as_float(CJ.y); \
          float wm = w * HJ; \
          S1 += wm; S2 += wm * HJ; \
          M = fmaxf(M, wm); m = fminf(m, wm); \
          if (PRED){ \
            float sv = w * TJ; \
            if (sv > best){ best = sv; bi = CJ.x; } \
            else if (sv == best && CJ.x < bi) bi = CJ.x; \
          } \
        } } while(0)

      // prologue: csr for batch0 (c) and batch1 (p); h/t gathers for batch0
      int2 c0 = csr[eBeg+0], c1 = csr[eBeg+1], c2 = csr[eBeg+2], c3 = csr[eBeg+3];
      int2 c4 = csr[eBeg+4], c5 = csr[eBeg+5], c6 = csr[eBeg+6], c7 = csr[eBeg+7];
      int2 p0 = csr[eBeg+8], p1 = csr[eBeg+9], p2 = csr[eBeg+10], p3 = csr[eBeg+11];
      int2 p4 = csr[eBeg+12], p5 = csr[eBeg+13], p6 = csr[eBeg+14], p7 = csr[eBeg+15];
      float h0 = h[c0.x*32+lane], h1 = h[c1.x*32+lane], h2 = h[c2.x*32+lane], h3 = h[c3.x*32+lane];
      float h4 = h[c4.x*32+lane], h5 = h[c5.x*32+lane], h6 = h[c6.x*32+lane], h7 = h[c7.x*32+lane];
      float t0=0,t1=0,t2=0,t3=0,t4=0,t5=0,t6=0,t7=0;
      if (PRED){
        t0 = tdot[c0.x]; t1 = tdot[c1.x]; t2 = tdot[c2.x]; t3 = tdot[c3.x];
        t4 = tdot[c4.x]; t5 = tdot[c5.x]; t6 = tdot[c6.x]; t7 = tdot[c7.x];
      }

      int nfull = (eEnd - eBeg) >> 3;
      int e = eBeg;
      for (int b = 0; b < nfull; ++b, e += 8){
        // 2-ahead csr (pad covers up to eEnd+15)
        int en = e + 16;
        int2 q0 = csr[en+0], q1 = csr[en+1], q2 = csr[en+2], q3 = csr[en+3];
        int2 q4 = csr[en+4], q5 = csr[en+5], q6 = csr[en+6], q7 = csr[en+7];
        // gathers for NEXT batch (p csr loaded one iteration ago)
        float g0 = h[p0.x*32+lane], g1 = h[p1.x*32+lane], g2 = h[p2.x*32+lane], g3 = h[p3.x*32+lane];
        float g4 = h[p4.x*32+lane], g5 = h[p5.x*32+lane], g6 = h[p6.x*32+lane], g7 = h[p7.x*32+lane];
        float u0=0,u1=0,u2=0,u3=0,u4=0,u5=0,u6=0,u7=0;
        if (PRED){
          u0 = tdot[p0.x]; u1 = tdot[p1.x]; u2 = tdot[p2.x]; u3 = tdot[p3.x];
          u4 = tdot[p4.x]; u5 = tdot[p5.x]; u6 = tdot[p6.x]; u7 = tdot[p7.x];
        }
        // accumulate current batch (all values issued >= 1 iteration ago)
        ACCU(0, c0, h0, t0); ACCU(1, c1, h1, t1);
        ACCU(2, c2, h2, t2); ACCU(3, c3, h3, t3);
        ACCU(4, c4, h4, t4); ACCU(5, c5, h5, t5);
        ACCU(6, c6, h6, t6); ACCU(7, c7, h7, t7);
        c0=p0; c1=p1; c2=p2; c3=p3; c4=p4; c5=p5; c6=p6; c7=p7;
        p0=q0; p1=q1; p2=q2; p3=q3; p4=q4; p5=q5; p6=q6; p7=q7;
        h0=g0; h1=g1; h2=g2; h3=g3; h4=g4; h5=g5; h6=g6; h7=g7;
        if (PRED){ t0=u0; t1=u1; t2=u2; t3=u3; t4=u4; t5=u5; t6=u6; t7=u7; }
      }
      // tail batch (guarded)
      ACCG(0, c0, h0, t0); ACCG(1, c1, h1, t1);
      ACCG(2, c2, h2, t2); ACCG(3, c3, h3, t3);
      ACCG(4, c4, h4, t4); ACCG(5, c5, h5, t5);
      ACCG(6, c6, h6, t6); ACCG(7, c7, h7, t7);
      // trailing finalizes (incl. empty nodes)
      while (curn < ng0 + nend) FINALIZE();
#undef ACCU
#undef ACCG
#undef FINALIZE
    }
  }
  __syncthreads();

  // ---- phase 2: linear ----
  {
    const float* Wl = lin_W + (size_t)l * 13312;   // 416*32
    int lane = tid & 63;
    int j0 = __builtin_amdgcn_readfirstlane((tid >> 6) * 8);  // 0,8,16,24
    int n0 = base + lane;
    int n = (n0 < NN) ? n0 : NN-1;
    float sc = scale_arr[n], iv = inv_arr[n];
    float acc[8];
    #pragma unroll
    for (int j = 0; j < 8; ++j) acc[j] = lin_b[l*32 + j0 + j];

    for (int k = 0; k < 32; ++k){
      float xv = hT[k*NN + n];
      const float* wr = Wl + k*32 + j0;
      #pragma unroll
      for (int j = 0; j < 8; ++j) acc[j] += xv * wr[j];
    }
    for (int kp = 0; kp < 128; ++kp){
      float f = sh[kp*64 + (lane ^ (kp & 31))];
      int d = kp >> 2, c = kp & 3;
      const float* wr = Wl + (32 + d*12 + c*3)*32 + j0;
      float f1 = f*sc, f2 = f*iv;
      #pragma unroll
      for (int j = 0; j < 8; ++j)
        acc[j] += f*wr[j] + f1*wr[32+j] + f2*wr[64+j];
    }

    if (n0 < NN){
      #pragma unroll
      for (int j = 0; j < 8; ++j){
        float v = fmaxf(acc[j], 0.f);
        h_next[n0*32 + j0 + j] = v;
        hT_next[(j0+j)*NN + n0] = v;
      }
    }
  }
}

// ---------------- final MLP ----------------
__global__ __launch_bounds__(256) void k_mlp(const float* __restrict__ hT,
                                             const float* __restrict__ qc,
                                             const float* __restrict__ W1,
                                             const float* __restrict__ W2,
                                             const float* __restrict__ b2,
                                             float* __restrict__ out_score){
  int n0 = blockIdx.x*256 + threadIdx.x;
  int n = (n0 < NN) ? n0 : NN-1;
  float acc[64];
  #pragma unroll
  for (int j = 0; j < 64; ++j) acc[j] = qc[j];
  for (int k = 0; k < 32; ++k){
    float xv = hT[k*NN + n];
    const float* wr = W1 + k*64;
    #pragma unroll
    for (int j = 0; j < 64; ++j) acc[j] += xv * wr[j];
  }
  float s = b2[0];
  #pragma unroll
  for (int j = 0; j < 64; ++j) s += fmaxf(acc[j], 0.f) * W2[j];
  if (n0 < NN) out_score[n0] = s;
}

// ---------------- host launch ----------------
extern "C" void kernel_launch(void* const* d_in, const int* in_sizes, int n_in,
                              void* d_out, int out_size, void* d_ws, size_t ws_size,
                              hipStream_t stream){
  const int*   node_in  = (const int*)d_in[0];
  const int*   node_out = (const int*)d_in[1];
  const float* ew       = (const float*)d_in[2];
  const int*   hidx     = (const int*)d_in[3];
  const float* qw       = (const float*)d_in[4];
  const float* rel_W    = (const float*)d_in[5];
  const float* rel_b    = (const float*)d_in[6];
  const float* lin_W    = (const float*)d_in[7];
  const float* lin_b    = (const float*)d_in[8];
  const float* W1       = (const float*)d_in[9];
  const float* b1       = (const float*)d_in[10];
  const float* W2       = (const float*)d_in[11];
  const float* b2       = (const float*)d_in[12];
  float* out_score = (float*)d_out;
  float* out_pred  = out_score + NN;

  char* w = (char*)d_ws;
  size_t off = 0;
  auto take = [&](size_t bytes)->char*{
    char* p = w + off;
    off = (off + bytes + 255) & ~(size_t)255;
    return p;
  };
  double* deg_pack = (double*)take((size_t)NN*8 + 64*4);
  float*  logsum   = (float*)(deg_pack + NN);
  int*   row_start = (int*)take((size_t)(NN+1)*4);
  int*   cursor    = (int*)take((size_t)NN*4);
  int*   partials  = (int*)take(256*4);
  float* rel6      = (float*)take(192*4);
  float* qc        = (float*)take(64*4);
  float* scale_arr = (float*)take((size_t)NN*4);
  float* inv_arr   = (float*)take((size_t)NN*4);
  float* tdot      = (float*)take((size_t)NN*4);
  int2*  csr       = (int2*)take((size_t)(EE+32)*8);
  float* h_a       = (float*)take((size_t)NN*32*4);
  float* hT_a      = (float*)take((size_t)NN*32*4);
  float* h_b       = (float*)take((size_t)NN*32*4);
  float* hT_b      = (float*)take((size_t)NN*32*4);

  int zc = 2*NN + 64;   // N doubles == 2N floats, + logsum block
  int nb = (NN + 255) / 256;   // 196
  int nlb = (NN + 63) / 64;    // 782
  k_zero   <<<(zc+255)/256, 256, 0, stream>>>((float*)deg_pack, zc);
  k_hist   <<<(EE+255)/256, 256, 0, stream>>>(node_out, ew, deg_pack);
  k_logsum <<<nb, 256, 0, stream>>>(deg_pack, logsum);
  k_scan1  <<<nb, 256, 0, stream>>>(deg_pack, partials);
  k_scan2  <<<1, 256, 0, stream>>>(partials, nb, row_start, csr);
  k_scan3  <<<nb, 256, 0, stream>>>(deg_pack, partials, row_start, cursor);
  k_fillcsr<<<(EE+255)/256, 256, 0, stream>>>(node_in, node_out, ew, cursor, csr);
  k_scales <<<nb, 256, 0, stream>>>(deg_pack, logsum, scale_arr, inv_arr);
  k_prep   <<<1, 256, 0, stream>>>(qw, rel_W, rel_b, W1, b1, rel6, qc);
  k_init_h <<<(NN*DD+255)/256, 256, 0, stream>>>(hidx, h_a, hT_a);

  float* hc = h_a;  float* hTc = hT_a;
  float* hn = h_b;  float* hTn = hT_b;
  for (int l = 0; l < 6; ++l){
    if (l == 5){
      k_dot<<<nb, 256, 0, stream>>>(hc, rel6, tdot);
      k_layer<true><<<nlb, 256, 0, stream>>>(hc, hTc, rel6, row_start, csr,
                                             hidx, tdot, lin_W, lin_b,
                                             scale_arr, inv_arr, hn, hTn,
                                             out_pred, l);
    } else {
      k_layer<false><<<nlb, 256, 0, stream>>>(hc, hTc, rel6, row_start, csr,
                                              hidx, tdot, lin_W, lin_b,
                                              scale_arr, inv_arr, hn, hTn,
                                              out_pred, l);
    }
    float* t1 = hc;  hc = hn;  hn = t1;
    float* t2 = hTc; hTc = hTn; hTn = t2;
  }
  k_mlp<<<nb, 256, 0, stream>>>(hTc, qc, W1, W2, b2, out_score);
}